// Round 5
// baseline (313.419 us; speedup 1.0000x reference)
//
#include <hip/hip_runtime.h>

// LightLIF fused step on MI355X (gfx950) — round 5.
//
//   A = [inputs | z]            : [4096, 3072] fp32   (M x K)
//   Bm = [w_in ; w_rec*(1-eye)] : [3072, 2048] fp32   (K x N), B pre-scaled by 256
//   i_t = A @ Bm    (fp32-accurate via f16 Markidis split, 3 MFMA passes)
//   new_v = DECAY*v + (1-DECAY)*i_t - 0.615*z ; spike vs THR
//   d_out = [new_z (M*N) | new_v (M*N)]
//
// Round-5: round-4 counters showed LDS reads and MFMA running SERIALLY
// (step = 4275 cyc ~= 1862 MFMA + 1920 LDS): the per-step barrier phase-locks
// all 8 waves into read-burst then MFMA-burst. Fix: A fragments are loaded
// DIRECTLY global->VGPR from the ws images (which are already in fragment
// layout; consecutive lanes -> consecutive 16 B), so only B flows through LDS
// (64 ds_read + 16 KB DMA ~= 900 cyc << 1862 MFMA). Grid swizzled so
// XCD = bm%8: each XCD's A step-slice (64 KB) is L2-resident and reused by
// its 16 bn-blocks. LDS = 2 x 16 KB static. Numerics bit-identical.

#define M_DIM 4096
#define N_DIM 2048
#define K_DIM 3072
#define KA    1024
#define BK    32
#define NSTEP (K_DIM / BK)          // 96
#define AIMG  8192                  // halves: 4 k-octets x 256 rows x 8
#define BIMG  4096                  // halves: 4 k-octets x 128 cols x 8

#define SZ_AH ((size_t)16 * 96 * AIMG * 2)  // 25,165,824 B (one of hi/lo)
#define SZ_BH ((size_t)16 * 96 * BIMG * 2)  // 12,582,912 B
#define WS_NEEDED (2 * SZ_AH + 2 * SZ_BH)   // 75,497,472 B

typedef _Float16 f16x8 __attribute__((ext_vector_type(8)));
typedef float    f32x4 __attribute__((ext_vector_type(4)));

#define GLOBAL_AS(p) ((const __attribute__((address_space(1))) void*)(p))
#define LDS_AS(p)    ((__attribute__((address_space(3))) void*)(p))

// hi/lo split with lo pre-scaled by 2048 (RNE conversions)
#define SPLIT(x, dsthi, dstlo, idx)                                  \
  {                                                                  \
    _Float16 _h = (_Float16)(x);                                     \
    float    _r = ((x) - (float)_h) * 2048.0f;                       \
    dsthi[idx] = _h;                                                 \
    dstlo[idx] = (_Float16)_r;                                       \
  }

// ---------------------------------------------------------------------------
// prep_a: split [inputs|z] into (hi,lo) f16 images, layout [kg][row 256][8].
// grid (96 kt, 16 bm), block 256.
// ---------------------------------------------------------------------------
__global__ void prep_a(const float* __restrict__ inputs,
                       const float* __restrict__ z,
                       _Float16* __restrict__ ahi, _Float16* __restrict__ alo) {
  const int kt = blockIdx.x, bm = blockIdx.y;
  const int t = threadIdx.x;
  const int s = t & 3;       // k-octet 0..3
  const int rr = t >> 2;     // 0..63
  const int k0 = kt * BK + s * 8;
  const size_t img = ((size_t)bm * 96 + kt) * AIMG;
#pragma unroll
  for (int p = 0; p < 4; ++p) {
    const int row = p * 64 + rr;
    const int rg = bm * 256 + row;
    const float* src = (kt < 32) ? inputs + (size_t)rg * KA + k0
                                 : z + (size_t)rg * N_DIM + (k0 - KA);
    const float4 f0 = *(const float4*)(src);
    const float4 f1 = *(const float4*)(src + 4);
    f16x8 hi, lo;
    SPLIT(f0.x, hi, lo, 0);
    SPLIT(f0.y, hi, lo, 1);
    SPLIT(f0.z, hi, lo, 2);
    SPLIT(f0.w, hi, lo, 3);
    SPLIT(f1.x, hi, lo, 4);
    SPLIT(f1.y, hi, lo, 5);
    SPLIT(f1.z, hi, lo, 6);
    SPLIT(f1.w, hi, lo, 7);
    const size_t o = img + (size_t)s * 2048 + (size_t)row * 8;
    *(f16x8*)&ahi[o] = hi;
    *(f16x8*)&alo[o] = lo;
  }
}

// ---------------------------------------------------------------------------
// prep_b: split w (x256, diag-masked) into transposed images [kg][col 128][8].
// grid (96 kt, 16 bn), block 128; thread owns one output column.
// ---------------------------------------------------------------------------
__global__ void prep_b(const float* __restrict__ w_in,
                       const float* __restrict__ w_rec,
                       _Float16* __restrict__ bhi, _Float16* __restrict__ blo) {
  const int kt = blockIdx.x, bn = blockIdx.y;
  const int c = threadIdx.x;      // 0..127
  const int ng = bn * 128 + c;
  const int k0 = kt * BK;
  f16x8 hi[4], lo[4];
#pragma unroll
  for (int kk = 0; kk < BK; ++kk) {
    const int k = k0 + kk;
    float x = (k < KA) ? w_in[(size_t)k * N_DIM + ng]
                       : w_rec[(size_t)(k - KA) * N_DIM + ng];
    if (k >= KA && (k - KA) == ng) x = 0.0f;   // zero diagonal of w_rec
    x *= 256.0f;                               // keep hi-parts normal in f16
    SPLIT(x, hi[kk >> 3], lo[kk >> 3], kk & 7);
  }
  const size_t img = ((size_t)bn * 96 + kt) * BIMG + (size_t)c * 8;
#pragma unroll
  for (int q = 0; q < 4; ++q) {
    *(f16x8*)&bhi[img + (size_t)q * 1024] = hi[q];
    *(f16x8*)&blo[img + (size_t)q * 1024] = lo[q];
  }
}

// ---------------------------------------------------------------------------
// GEMM + fused LIF epilogue. grid (16 bm, 16 bn) [x=bm -> XCD=bm%8], block 512
// (8 waves, 4m x 2n of 64x64). A frags: direct global->VGPR (images are in
// frag layout). B: double-buffered 32 KB LDS, staged by all 8 waves (2 KB ea),
// one barrier per K-step.
// ---------------------------------------------------------------------------
__global__ __launch_bounds__(512, 2) void lif_gemm(
    const _Float16* __restrict__ ahi, const _Float16* __restrict__ alo,
    const _Float16* __restrict__ bhi, const _Float16* __restrict__ blo,
    const float* __restrict__ vin, const float* __restrict__ zin,
    float* __restrict__ out) {
  __shared__ __align__(16) _Float16 sbuf[2][2 * BIMG];  // 32 KB total

  const int tid = threadIdx.x;
  const int bm = blockIdx.x;      // x-major so XCD = bm % 8 (A L2-locality)
  const int bn = blockIdx.y;
  const int lane = tid & 63;
  const int wid = tid >> 6;       // 0..7
  const int wm = wid & 3;         // m-quadrant (4 x 64)
  const int wn = wid >> 2;        // n-half (2 x 64)
  const int lr = lane & 15;
  const int kg = lane >> 4;

  // ---- A direct-load bases: per-lane byte offset into the (bm) image run ----
  // image layout: [kg][row 256][8 halves]; frag i rows = wm*64 + i*16 + lr.
  const size_t abyte = (size_t)kg * 4096 + (size_t)(wm * 64 + lr) * 16;
  const char* gAh = (const char*)(ahi + ((size_t)bm * 96) * AIMG) + abyte;
  const char* gAl = (const char*)(alo + ((size_t)bm * 96) * AIMG) + abyte;

  // ---- B staging: wave wid stages 2 KB of the 16 KB (Bhi|Blo) step-slice ----
  const _Float16* gsB;
  if (wid < 4) gsB = bhi + ((size_t)bn * 96) * BIMG + wid * 1024;
  else         gsB = blo + ((size_t)bn * 96) * BIMG + (wid - 4) * 1024;
  gsB += (size_t)lane * 8;            // per-lane 16 B
  const int lofsB = wid * 1024;       // halves within [Bhi 4096 | Blo 4096]

  // B frag offset (halves) within Bhi/Blo region: [kg][col 128][8]
  const int bbase = kg * 1024 + (wn * 64 + lr) * 8;

  f32x4 acc0[4][4];  // hi*hi (scale 256)
  f32x4 acc1[4][4];  // hi*lo + lo*hi (scale 256*2048)
#pragma unroll
  for (int i = 0; i < 4; ++i)
#pragma unroll
    for (int j = 0; j < 4; ++j) {
      acc0[i][j] = (f32x4)0.0f;
      acc1[i][j] = (f32x4)0.0f;
    }

  // prologue: stage B(kt=0) into buffer 0
  {
    _Float16* l = &sbuf[0][lofsB];
    __builtin_amdgcn_global_load_lds(GLOBAL_AS(gsB), LDS_AS(l), 16, 0, 0);
    __builtin_amdgcn_global_load_lds(GLOBAL_AS(gsB + 512), LDS_AS(l + 512), 16, 0, 0);
  }

  for (int kt = 0; kt < NSTEP; ++kt) {
    __syncthreads();  // B(kt) staged; buf^1 consumers done

    // prefetch B(kt+1) into the other buffer (drained at next barrier)
    if (kt + 1 < NSTEP) {
      const _Float16* g = gsB + (size_t)(kt + 1) * BIMG;
      _Float16* l = &sbuf[(kt + 1) & 1][lofsB];
      __builtin_amdgcn_global_load_lds(GLOBAL_AS(g), LDS_AS(l), 16, 0, 0);
      __builtin_amdgcn_global_load_lds(GLOBAL_AS(g + 512), LDS_AS(l + 512), 16, 0, 0);
    }

    // A fragments: direct global->VGPR (coalesced 16 B/lane; L1/L2-served)
    const char* pAh = gAh + (size_t)kt * (AIMG * 2);
    const char* pAl = gAl + (size_t)kt * (AIMG * 2);
    f16x8 ah[4], al[4];
#pragma unroll
    for (int i = 0; i < 4; ++i) {
      ah[i] = *(const f16x8*)(pAh + i * 256);
      al[i] = *(const f16x8*)(pAl + i * 256);
    }

    const _Float16* pBhi = &sbuf[kt & 1][0];
    const _Float16* pBlo = pBhi + BIMG;
#pragma unroll
    for (int j = 0; j < 4; ++j) {
      const f16x8 bh = *(const f16x8*)&pBhi[bbase + j * 128];
      const f16x8 bl = *(const f16x8*)&pBlo[bbase + j * 128];
#pragma unroll
      for (int i = 0; i < 4; ++i)
        acc0[i][j] = __builtin_amdgcn_mfma_f32_16x16x32_f16(ah[i], bh, acc0[i][j], 0, 0, 0);
#pragma unroll
      for (int i = 0; i < 4; ++i)
        acc1[i][j] = __builtin_amdgcn_mfma_f32_16x16x32_f16(ah[i], bl, acc1[i][j], 0, 0, 0);
#pragma unroll
      for (int i = 0; i < 4; ++i)
        acc1[i][j] = __builtin_amdgcn_mfma_f32_16x16x32_f16(al[i], bh, acc1[i][j], 0, 0, 0);
    }
  }

  // fused LIF epilogue
  const float DECAYF = 0.9512294245007140f;
  const float OMD = 1.0f - DECAYF;
  const float THR = 0.615f;

  float* outZ = out;
  float* outV = out + (size_t)M_DIM * N_DIM;
  const int colbase = bn * 128 + wn * 64;
  const int rowbase = bm * 256 + wm * 64 + kg * 4;

#pragma unroll
  for (int i = 0; i < 4; ++i) {
#pragma unroll
    for (int j = 0; j < 4; ++j) {
      const int col = colbase + j * 16 + lr;
#pragma unroll
      for (int r = 0; r < 4; ++r) {
        const int row = rowbase + i * 16 + r;
        const size_t idx = (size_t)row * N_DIM + col;
        const float it = acc0[i][j][r] * (1.0f / 256.0f) +
                         acc1[i][j][r] * (1.0f / 524288.0f);
        const float vv = vin[idx];
        const float zz = zin[idx];
        const float nv = DECAYF * vv + OMD * it - THR * zz;
        const float vs = (nv - THR) / THR;
        outZ[idx] = (vs > THR) ? 1.0f : 0.0f;
        outV[idx] = nv;
      }
    }
  }
}

// ---------------------------------------------------------------------------
// Fallback (round-1 monolithic kernel) — used only if ws_size < WS_NEEDED.
// ---------------------------------------------------------------------------
#define LDK 40
__global__ __launch_bounds__(256, 2) void lif_kernel(
    const float* __restrict__ inputs, const float* __restrict__ vin,
    const float* __restrict__ zin, const float* __restrict__ w_in,
    const float* __restrict__ w_rec, float* __restrict__ out) {
  __shared__ __align__(16) _Float16 sAhi[128 * LDK];
  __shared__ __align__(16) _Float16 sAlo[128 * LDK];
  __shared__ __align__(16) _Float16 sBhi[128 * LDK];
  __shared__ __align__(16) _Float16 sBlo[128 * LDK];

  const int tid = threadIdx.x;
  const int bn = blockIdx.x;
  const int bm = blockIdx.y;
  const int srow = tid & 127;
  const int skh = tid >> 7;
  const int lane = tid & 63;
  const int wid = tid >> 6;
  const int wm = wid & 1;
  const int wn = wid >> 1;
  const int lr = lane & 15;
  const int kg = lane >> 4;
  const int aoff = (wm * 64 + lr) * LDK + kg * 8;
  const int boff = (wn * 64 + lr) * LDK + kg * 8;

  f32x4 acc0[4][4];
  f32x4 acc1[4][4];
#pragma unroll
  for (int i = 0; i < 4; ++i)
#pragma unroll
    for (int j = 0; j < 4; ++j) {
      acc0[i][j] = (f32x4)0.0f;
      acc1[i][j] = (f32x4)0.0f;
    }

  const int rowg = bm * 128 + srow;
  const int ng = bn * 128 + srow;

  for (int kt = 0; kt < NSTEP; ++kt) {
    const int k0 = kt * BK;
    f16x8 ahi[2], alo[2];
    {
      const float* aptr = (k0 < KA)
          ? inputs + (size_t)rowg * KA + (k0 + skh * 16)
          : zin + (size_t)rowg * N_DIM + (k0 - KA + skh * 16);
#pragma unroll
      for (int q = 0; q < 4; ++q) {
        const float4 f = *(const float4*)(aptr + q * 4);
        const int vi = q >> 1, ei = (q & 1) * 4;
        SPLIT(f.x, ahi[vi], alo[vi], ei + 0);
        SPLIT(f.y, ahi[vi], alo[vi], ei + 1);
        SPLIT(f.z, ahi[vi], alo[vi], ei + 2);
        SPLIT(f.w, ahi[vi], alo[vi], ei + 3);
      }
    }
    f16x8 bhi[2], blo[2];
    {
      const bool isrec = (k0 >= KA);
      const int kbase = k0 - KA + skh * 16;
      const float* bptr = isrec
          ? w_rec + (size_t)kbase * N_DIM + ng
          : w_in + (size_t)(k0 + skh * 16) * N_DIM + ng;
#pragma unroll
      for (int kk = 0; kk < 16; ++kk) {
        float x = bptr[(size_t)kk * N_DIM];
        if (isrec && (kbase + kk == ng)) x = 0.0f;
        x *= 256.0f;
        SPLIT(x, bhi[kk >> 3], blo[kk >> 3], kk & 7);
      }
    }

    __syncthreads();
    {
      _Float16* pA = &sAhi[srow * LDK + skh * 16];
      *(f16x8*)(pA + 0) = ahi[0];
      *(f16x8*)(pA + 8) = ahi[1];
      _Float16* pAl = &sAlo[srow * LDK + skh * 16];
      *(f16x8*)(pAl + 0) = alo[0];
      *(f16x8*)(pAl + 8) = alo[1];
      _Float16* pB = &sBhi[srow * LDK + skh * 16];
      *(f16x8*)(pB + 0) = bhi[0];
      *(f16x8*)(pB + 8) = bhi[1];
      _Float16* pBl = &sBlo[srow * LDK + skh * 16];
      *(f16x8*)(pBl + 0) = blo[0];
      *(f16x8*)(pBl + 8) = blo[1];
    }
    __syncthreads();

    f16x8 ah[4], al[4];
#pragma unroll
    for (int i = 0; i < 4; ++i) {
      ah[i] = *(const f16x8*)&sAhi[aoff + i * 16 * LDK];
      al[i] = *(const f16x8*)&sAlo[aoff + i * 16 * LDK];
    }
#pragma unroll
    for (int j = 0; j < 4; ++j) {
      const f16x8 bh = *(const f16x8*)&sBhi[boff + j * 16 * LDK];
      const f16x8 bl = *(const f16x8*)&sBlo[boff + j * 16 * LDK];
#pragma unroll
      for (int i = 0; i < 4; ++i)
        acc0[i][j] = __builtin_amdgcn_mfma_f32_16x16x32_f16(ah[i], bh, acc0[i][j], 0, 0, 0);
#pragma unroll
      for (int i = 0; i < 4; ++i)
        acc1[i][j] = __builtin_amdgcn_mfma_f32_16x16x32_f16(ah[i], bl, acc1[i][j], 0, 0, 0);
#pragma unroll
      for (int i = 0; i < 4; ++i)
        acc1[i][j] = __builtin_amdgcn_mfma_f32_16x16x32_f16(al[i], bh, acc1[i][j], 0, 0, 0);
    }
  }

  const float DECAYF = 0.9512294245007140f;
  const float OMD = 1.0f - DECAYF;
  const float THR = 0.615f;
  float* outZ = out;
  float* outV = out + (size_t)M_DIM * N_DIM;
  const int colbase = bn * 128 + wn * 64;
  const int rowbase = bm * 128 + wm * 64 + kg * 4;
#pragma unroll
  for (int i = 0; i < 4; ++i) {
#pragma unroll
    for (int j = 0; j < 4; ++j) {
      const int col = colbase + j * 16 + lr;
#pragma unroll
      for (int r = 0; r < 4; ++r) {
        const int row = rowbase + i * 16 + r;
        const size_t idx = (size_t)row * N_DIM + col;
        const float it = acc0[i][j][r] * (1.0f / 256.0f) +
                         acc1[i][j][r] * (1.0f / 524288.0f);
        const float vv = vin[idx];
        const float zz = zin[idx];
        const float nv = DECAYF * vv + OMD * it - THR * zz;
        const float vs = (nv - THR) / THR;
        outZ[idx] = (vs > THR) ? 1.0f : 0.0f;
        outV[idx] = nv;
      }
    }
  }
}

extern "C" void kernel_launch(void* const* d_in, const int* in_sizes, int n_in,
                              void* d_out, int out_size, void* d_ws, size_t ws_size,
                              hipStream_t stream) {
  const float* inputs = (const float*)d_in[0];
  const float* v      = (const float*)d_in[1];
  const float* z      = (const float*)d_in[2];
  const float* w_in   = (const float*)d_in[3];
  const float* w_rec  = (const float*)d_in[4];
  float* out = (float*)d_out;

  if (ws_size >= WS_NEEDED) {
    _Float16* ahi = (_Float16*)d_ws;
    _Float16* alo = (_Float16*)((char*)d_ws + SZ_AH);
    _Float16* bhi = (_Float16*)((char*)d_ws + 2 * SZ_AH);
    _Float16* blo = (_Float16*)((char*)d_ws + 2 * SZ_AH + SZ_BH);

    hipLaunchKernelGGL(prep_a, dim3(96, 16), dim3(256), 0, stream,
                       inputs, z, ahi, alo);
    hipLaunchKernelGGL(prep_b, dim3(96, 16), dim3(128), 0, stream,
                       w_in, w_rec, bhi, blo);
    // grid x = bm so XCD (= linear blockId % 8) keys on bm -> A L2-locality
    hipLaunchKernelGGL(lif_gemm, dim3(16, 16), dim3(512), 0, stream,
                       ahi, alo, bhi, blo, v, z, out);
  } else {
    hipLaunchKernelGGL(lif_kernel, dim3(16, 32), dim3(256), 0, stream,
                       inputs, v, z, w_in, w_rec, out);
  }
}